// Round 10
// baseline (19424.126 us; speedup 1.0000x reference)
//
#include <hip/hip_runtime.h>
#include <hip/hip_bf16.h>
#include <math.h>

// NOVAE forward. Round 10: LDS-resident-K Sinkhorn.
//  - sinkhorn_lds: 256 persistent blocks, block b holds K rows [16b,16b+16)
//    in 128 KiB LDS (one-time 33.5 MB load; gfx950 LDS = 160 KiB/CU).
//    Per iter: Phase A partial column-sums -> P (4 MB), barrier, Phase B
//    256-way column reduce -> v, barrier, Phase C LDS row-dots -> u (local).
//    Replaces the 67 MB/iter L3 stream (measured ceiling ~17 TB/s, R4)
//    with ~12 MB/iter of P/v traffic. K^T never needed -> exp kernel is
//    elementwise (no transpose).
//  - everything else byte-identical to R9 (1178 us banked; revert point).

namespace {

constexpr float REG = 0.05f;
constexpr int SINK_ITERS = 200;
constexpr int NBLK = 256;
constexpr int NGRP = NBLK / 32;

typedef __attribute__((ext_vector_type(8))) short bf16x8;
typedef __attribute__((ext_vector_type(4))) float f32x4;

__device__ __forceinline__ unsigned short f2bf(float f)
{
    return __hip_bfloat16_raw(__float2bfloat16(f)).x;
}
__device__ __forceinline__ float bf2f(unsigned short u)
{
    return __uint_as_float(((unsigned int)u) << 16);
}
__device__ __forceinline__ float blo(unsigned int x) { return __uint_as_float(x << 16); }
__device__ __forceinline__ float bhi(unsigned int x) { return __uint_as_float(x & 0xffff0000u); }

enum { EPI_SPLIT_RELU = 0, EPI_COST = 1 };

// ---------- 128x128 split-bf16x2 MFMA GEMM (R7/R9 verbatim) ----------
template<int EPI>
__global__ __launch_bounds__(256)
void gemm128_split(const unsigned short* __restrict__ Ah,
                   const unsigned short* __restrict__ Al,
                   const unsigned short* __restrict__ Bh,
                   const unsigned short* __restrict__ Bl,
                   const float* __restrict__ rb,
                   const float* __restrict__ aux,
                   void* __restrict__ C0,
                   unsigned short* __restrict__ C1,
                   float* __restrict__ maxOut,
                   int M, int N, int K)
{
    constexpr int LDK = 40;
    __shared__ unsigned short sAh[128 * LDK], sAl[128 * LDK];
    __shared__ unsigned short sBh[128 * LDK], sBl[128 * LDK];
    __shared__ float red[256];

    const int t = threadIdx.x;
    const int w = t >> 6, lane = t & 63;
    const int wr = (w >> 1) * 64, wc = (w & 1) * 64;
    const int am = lane & 15, aq = lane >> 4;
    const int row0 = blockIdx.y * 128, col0 = blockIdx.x * 128;
    const int sr0 = t >> 2, sc = (t & 3) << 3;

    f32x4 acc[4][4] = {};

    for (int k0 = 0; k0 < K; k0 += 32) {
        #pragma unroll
        for (int p = 0; p < 2; ++p) {
            const int r = sr0 + p * 64;
            const size_t ga = (size_t)(row0 + r) * K + k0 + sc;
            const size_t gb = (size_t)(col0 + r) * K + k0 + sc;
            *(uint4*)&sAh[r * LDK + sc] = *(const uint4*)&Ah[ga];
            *(uint4*)&sAl[r * LDK + sc] = *(const uint4*)&Al[ga];
            *(uint4*)&sBh[r * LDK + sc] = *(const uint4*)&Bh[gb];
            *(uint4*)&sBl[r * LDK + sc] = *(const uint4*)&Bl[gb];
        }
        __syncthreads();
        bf16x8 ah[4], al[4], bh[4], bl[4];
        #pragma unroll
        for (int i = 0; i < 4; ++i) {
            const int ra = (wr + i * 16 + am) * LDK + aq * 8;
            const int rbx = (wc + i * 16 + am) * LDK + aq * 8;
            ah[i] = *(const bf16x8*)&sAh[ra];
            al[i] = *(const bf16x8*)&sAl[ra];
            bh[i] = *(const bf16x8*)&sBh[rbx];
            bl[i] = *(const bf16x8*)&sBl[rbx];
        }
        #pragma unroll
        for (int i = 0; i < 4; ++i)
            #pragma unroll
            for (int j = 0; j < 4; ++j) {
                acc[i][j] = __builtin_amdgcn_mfma_f32_16x16x32_bf16(ah[i], bh[j], acc[i][j], 0, 0, 0);
                acc[i][j] = __builtin_amdgcn_mfma_f32_16x16x32_bf16(al[i], bh[j], acc[i][j], 0, 0, 0);
                acc[i][j] = __builtin_amdgcn_mfma_f32_16x16x32_bf16(ah[i], bl[j], acc[i][j], 0, 0, 0);
            }
        __syncthreads();
    }

    if constexpr (EPI == EPI_COST) {
        float lmax = 0.0f;
        #pragma unroll
        for (int i = 0; i < 4; ++i) {
            #pragma unroll
            for (int r = 0; r < 4; ++r) {
                const int row = row0 + wr + i * 16 + aq * 4 + r;
                const float znr = rb[row];
                #pragma unroll
                for (int j = 0; j < 4; ++j) {
                    const int col = col0 + wc + j * 16 + am;
                    const float v = fmaxf(znr + aux[col] - 2.0f * acc[i][j][r], 0.0f);
                    ((float*)C0)[(size_t)row * N + col] = v;
                    lmax = fmaxf(lmax, v);
                }
            }
        }
        red[t] = lmax;
        __syncthreads();
        for (int s = 128; s > 0; s >>= 1) {
            if (t < s) red[t] = fmaxf(red[t], red[t + s]);
            __syncthreads();
        }
        if (t == 0) atomicMax((int*)maxOut, __float_as_int(red[0]));
    } else {
        #pragma unroll
        for (int j = 0; j < 4; ++j) {
            const int col = col0 + wc + j * 16 + am;
            const float b = rb[col];
            #pragma unroll
            for (int i = 0; i < 4; ++i)
                #pragma unroll
                for (int r = 0; r < 4; ++r) {
                    const int row = row0 + wr + i * 16 + aq * 4 + r;
                    const float v = fmaxf(acc[i][j][r] + b, 0.0f);
                    const unsigned short hi = f2bf(v);
                    ((unsigned short*)C0)[(size_t)row * N + col] = hi;
                    C1[(size_t)row * N + col] = f2bf(v - bf2f(hi));
                }
        }
    }
}

// ---------- encoder L3: split MFMA, fused split+rownorm (R9 verbatim) ----------
__global__ __launch_bounds__(256)
void gemm_l3_fused(const unsigned short* __restrict__ Ah,
                   const unsigned short* __restrict__ Al,
                   const unsigned short* __restrict__ Bth,
                   const unsigned short* __restrict__ Btl,
                   const float* __restrict__ bias,
                   unsigned short* __restrict__ zh,
                   unsigned short* __restrict__ zl,
                   float* __restrict__ zn)
{
    constexpr int K = 512, N = 128, LDK = 40;
    __shared__ unsigned short sAh[64 * LDK], sAl[64 * LDK];
    __shared__ unsigned short sBh[128 * LDK], sBl[128 * LDK];
    const int t = threadIdx.x;
    const int w = t >> 6, l = t & 63;
    const int am = l & 15, aq = l >> 4;
    const int row0 = blockIdx.x * 64;
    const int sr = t >> 2, sk = (t & 3) << 3;

    f32x4 acc[8] = {};
    for (int k0 = 0; k0 < K; k0 += 32) {
        {
            const size_t ga = (size_t)(row0 + sr) * K + k0 + sk;
            *(uint4*)&sAh[sr * LDK + sk] = *(const uint4*)&Ah[ga];
            *(uint4*)&sAl[sr * LDK + sk] = *(const uint4*)&Al[ga];
        }
        #pragma unroll
        for (int p = 0; p < 2; ++p) {
            const int s = t + p * 256;
            const int rb = s >> 2, kb = (s & 3) << 3;
            const size_t gb = (size_t)rb * K + k0 + kb;
            *(uint4*)&sBh[rb * LDK + kb] = *(const uint4*)&Bth[gb];
            *(uint4*)&sBl[rb * LDK + kb] = *(const uint4*)&Btl[gb];
        }
        __syncthreads();
        const bf16x8 ah = *(const bf16x8*)&sAh[(w * 16 + am) * LDK + aq * 8];
        const bf16x8 al = *(const bf16x8*)&sAl[(w * 16 + am) * LDK + aq * 8];
        #pragma unroll
        for (int j = 0; j < 8; ++j) {
            const bf16x8 bh = *(const bf16x8*)&sBh[(j * 16 + am) * LDK + aq * 8];
            const bf16x8 bl = *(const bf16x8*)&sBl[(j * 16 + am) * LDK + aq * 8];
            acc[j] = __builtin_amdgcn_mfma_f32_16x16x32_bf16(ah, bh, acc[j], 0, 0, 0);
            acc[j] = __builtin_amdgcn_mfma_f32_16x16x32_bf16(al, bh, acc[j], 0, 0, 0);
            acc[j] = __builtin_amdgcn_mfma_f32_16x16x32_bf16(ah, bl, acc[j], 0, 0, 0);
        }
        __syncthreads();
    }

    float pn4[4] = {0.0f, 0.0f, 0.0f, 0.0f};
    #pragma unroll
    for (int j = 0; j < 8; ++j) {
        const int col = j * 16 + am;
        const float b = bias[col];
        #pragma unroll
        for (int r = 0; r < 4; ++r) {
            const int row = row0 + w * 16 + aq * 4 + r;
            const float z = acc[j][r] + b;
            const unsigned short hi = f2bf(z);
            zh[(size_t)row * N + col] = hi;
            zl[(size_t)row * N + col] = f2bf(z - bf2f(hi));
            pn4[r] = fmaf(z, z, pn4[r]);
        }
    }
    #pragma unroll
    for (int r = 0; r < 4; ++r) {
        float s = pn4[r];
        #pragma unroll
        for (int o = 8; o > 0; o >>= 1) s += __shfl_down(s, o, 16);
        if (am == 0) zn[row0 + w * 16 + aq * 4 + r] = s;
    }
}

// ---------- plain bf16 MFMA GEMM (decoder + coupling), 64x64 tile ----------
template<bool RELU, bool OUT_BF16, bool ROWSCALE>
__global__ __launch_bounds__(256)
void gemm_bf16_bt(const unsigned short* __restrict__ A,
                  const unsigned short* __restrict__ Bt,
                  const float* __restrict__ bias,
                  const float* __restrict__ rs,
                  void* __restrict__ C, int M, int N, int K)
{
    constexpr int BK = 32, LDK = 40;
    __shared__ unsigned short sA[64 * LDK];
    __shared__ unsigned short sB[64 * LDK];
    const int t = threadIdx.x;
    const int w = t >> 6, l = t & 63;
    const int row0 = blockIdx.y * 64, col0 = blockIdx.x * 64;
    const int sr = t >> 2, sk = (t & 3) << 3;
    const int am = l & 15, aq = l >> 4;

    f32x4 acc[4] = {};
    for (int k0 = 0; k0 < K; k0 += BK) {
        *(uint4*)&sA[sr * LDK + sk] = *(const uint4*)&A [(size_t)(row0 + sr) * K + k0 + sk];
        *(uint4*)&sB[sr * LDK + sk] = *(const uint4*)&Bt[(size_t)(col0 + sr) * K + k0 + sk];
        __syncthreads();
        const bf16x8 af = *(const bf16x8*)&sA[(w * 16 + am) * LDK + aq * 8];
        #pragma unroll
        for (int c = 0; c < 4; ++c) {
            const bf16x8 bfr = *(const bf16x8*)&sB[(c * 16 + am) * LDK + aq * 8];
            acc[c] = __builtin_amdgcn_mfma_f32_16x16x32_bf16(af, bfr, acc[c], 0, 0, 0);
        }
        __syncthreads();
    }
    #pragma unroll
    for (int c = 0; c < 4; ++c) {
        const int col = col0 + c * 16 + am;
        const float b = bias ? bias[col] : 0.0f;
        #pragma unroll
        for (int r = 0; r < 4; ++r) {
            const int row = row0 + w * 16 + aq * 4 + r;
            float v = acc[c][r] + b;
            if constexpr (RELU) v = fmaxf(v, 0.0f);
            if constexpr (ROWSCALE) v *= rs[row];
            if constexpr (OUT_BF16)
                ((unsigned short*)C)[(size_t)row * N + col] = f2bf(v);
            else
                ((float*)C)[(size_t)row * N + col] = v;
        }
    }
}

// ---------- prep bodies (R9 verbatim) ----------
__device__ __forceinline__
void split_body(const float* __restrict__ x, unsigned short* __restrict__ hi,
                unsigned short* __restrict__ lo, int blk)
{
    const int i4 = (blk * 256 + threadIdx.x) * 4;
    const float4 v = *(const float4*)&x[i4];
    const float vv[4] = {v.x, v.y, v.z, v.w};
    unsigned short h[4], l[4];
    #pragma unroll
    for (int k = 0; k < 4; ++k) {
        h[k] = f2bf(vv[k]);
        l[k] = f2bf(vv[k] - bf2f(h[k]));
    }
    *(uint2*)&hi[i4] = *(uint2*)h;
    *(uint2*)&lo[i4] = *(uint2*)l;
}

__device__ __forceinline__
void wtrans_split_body(const float* __restrict__ W, unsigned short* __restrict__ Wth,
                       unsigned short* __restrict__ Wtl, int K, int N, int bx, int by)
{
    __shared__ float tile[32][33];
    const int tx = threadIdx.x & 31, ty4 = threadIdx.x >> 5;
    const int k0 = by * 32, n0 = bx * 32;
    #pragma unroll
    for (int r = 0; r < 4; ++r)
        tile[ty4 * 4 + r][tx] = W[(size_t)(k0 + ty4 * 4 + r) * N + n0 + tx];
    __syncthreads();
    #pragma unroll
    for (int r = 0; r < 4; ++r) {
        const float v = tile[tx][ty4 * 4 + r];
        const unsigned short h = f2bf(v);
        const size_t idx = (size_t)(n0 + ty4 * 4 + r) * K + k0 + tx;
        Wth[idx] = h;
        if (Wtl) Wtl[idx] = f2bf(v - bf2f(h));
    }
}

__global__ __launch_bounds__(256)
void prep_k(const float* __restrict__ zp,
            unsigned short* __restrict__ zph, unsigned short* __restrict__ zpl,
            const float* __restrict__ ew0, unsigned short* w0th, unsigned short* w0tl,
            const float* __restrict__ ew1, unsigned short* w1th, unsigned short* w1tl,
            const float* __restrict__ ew2, unsigned short* w2th, unsigned short* w2tl,
            const float* __restrict__ ew3, unsigned short* w3th, unsigned short* w3tl,
            const float* __restrict__ dw0, unsigned short* dwt0,
            const float* __restrict__ dw1, unsigned short* dwt1,
            const float* __restrict__ dw2, unsigned short* dwt2,
            const float* __restrict__ dw3, unsigned short* dwt3,
            float* __restrict__ pn,
            float* __restrict__ u, float* __restrict__ v,
            float* __restrict__ mx, int* __restrict__ bar)
{
    const int b = blockIdx.x;
    if (b < 512) {
        split_body(zp, zph, zpl, b);
    } else if (b < 1024) {
        const int j = b - 512; wtrans_split_body(ew0, w0th, w0tl, 1024, 512, j % 16, j / 16);
    } else if (b < 1536) {
        const int j = b - 1024; wtrans_split_body(ew1, w1th, w1tl, 512, 1024, j % 32, j / 32);
    } else if (b < 2048) {
        const int j = b - 1536; wtrans_split_body(ew2, w2th, w2tl, 1024, 512, j % 16, j / 16);
    } else if (b < 2112) {
        const int j = b - 2048; wtrans_split_body(ew3, w3th, w3tl, 512, 128, j % 4, j / 4);
    } else if (b < 2176) {
        const int j = b - 2112; wtrans_split_body(dw0, dwt0, nullptr, 128, 512, j % 16, j / 16);
    } else if (b < 2688) {
        const int j = b - 2176; wtrans_split_body(dw1, dwt1, nullptr, 512, 1024, j % 32, j / 32);
    } else if (b < 3200) {
        const int j = b - 2688; wtrans_split_body(dw2, dwt2, nullptr, 1024, 512, j % 16, j / 16);
    } else if (b < 3712) {
        const int j = b - 3200; wtrans_split_body(dw3, dwt3, nullptr, 512, 1024, j % 32, j / 32);
    } else if (b < 4736) {
        const int blk = b - 3712;
        const int row = blk * 4 + (threadIdx.x >> 6);
        const int lane = threadIdx.x & 63;
        const float2 vv = ((const float2*)&zp[(size_t)row * 128])[lane];
        float s = fmaf(vv.x, vv.x, vv.y * vv.y);
        #pragma unroll
        for (int o = 32; o > 0; o >>= 1) s += __shfl_down(s, o);
        if (lane == 0) pn[row] = s;
    } else {
        const int i = (b - 4736) * 256 + threadIdx.x;
        if (i < 4096) { u[i] = 1.0f / 4096.0f; v[i] = 1.0f / 4096.0f; }
        if (i == 0) *mx = 0.0f;
        if (b == 4736 && threadIdx.x < 32) bar[threadIdx.x] = 0;
    }
}

__global__ __launch_bounds__(256)
void split_k(const float* __restrict__ x, unsigned short* __restrict__ hi,
             unsigned short* __restrict__ lo)
{
    split_body(x, hi, lo, blockIdx.x);
}

__global__ __launch_bounds__(256)
void vscale_t_k(const float* __restrict__ zp, const float* __restrict__ v,
                unsigned short* __restrict__ W2t)
{
    __shared__ float tile[32][33];
    const int tx = threadIdx.x & 31, ty4 = threadIdx.x >> 5;
    const int j0 = blockIdx.y * 32, d0 = blockIdx.x * 32;
    #pragma unroll
    for (int r = 0; r < 4; ++r) {
        const int j = j0 + ty4 * 4 + r;
        tile[ty4 * 4 + r][tx] = v[j] * zp[(size_t)j * 128 + d0 + tx];
    }
    __syncthreads();
    #pragma unroll
    for (int r = 0; r < 4; ++r)
        W2t[(size_t)(d0 + ty4 * 4 + r) * 4096 + j0 + tx] = f2bf(tile[tx][ty4 * 4 + r]);
}

// K = exp(-M/(reg*(maxM+1e-12))) -> bf16, elementwise (no transpose needed)
__global__ __launch_bounds__(256)
void exp_k(const float* __restrict__ M, unsigned short* __restrict__ Kb,
           const float* __restrict__ mx)
{
    const float s = -1.0f / (REG * (*mx + 1e-12f));
    const size_t i8 = ((size_t)blockIdx.x * 256 + threadIdx.x) * 8;
    const float4 a = *(const float4*)&M[i8];
    const float4 b = *(const float4*)&M[i8 + 4];
    unsigned short h[8];
    h[0] = f2bf(expf(a.x * s)); h[1] = f2bf(expf(a.y * s));
    h[2] = f2bf(expf(a.z * s)); h[3] = f2bf(expf(a.w * s));
    h[4] = f2bf(expf(b.x * s)); h[5] = f2bf(expf(b.y * s));
    h[6] = f2bf(expf(b.z * s)); h[7] = f2bf(expf(b.w * s));
    *(uint4*)&Kb[i8] = *(uint4*)h;
}

// ---------- Sinkhorn: LDS-resident K ----------
__device__ __forceinline__
void grid_barrier(int* lcnt, int* gcnt, int* ggen)
{
    __syncthreads();
    if (threadIdx.x == 0) {
        __threadfence();
        const int gi = blockIdx.x & (NGRP - 1);
        const int g = __hip_atomic_load(ggen, __ATOMIC_RELAXED, __HIP_MEMORY_SCOPE_AGENT);
        if (__hip_atomic_fetch_add(&lcnt[gi], 1, __ATOMIC_ACQ_REL, __HIP_MEMORY_SCOPE_AGENT) == 31) {
            if (__hip_atomic_fetch_add(gcnt, 1, __ATOMIC_ACQ_REL, __HIP_MEMORY_SCOPE_AGENT) == NGRP - 1) {
                #pragma unroll
                for (int i = 0; i < NGRP; ++i)
                    __hip_atomic_store(&lcnt[i], 0, __ATOMIC_RELAXED, __HIP_MEMORY_SCOPE_AGENT);
                __hip_atomic_store(gcnt, 0, __ATOMIC_RELAXED, __HIP_MEMORY_SCOPE_AGENT);
                __hip_atomic_store(ggen, g + 1, __ATOMIC_RELEASE, __HIP_MEMORY_SCOPE_AGENT);
            } else {
                while (__hip_atomic_load(ggen, __ATOMIC_ACQUIRE, __HIP_MEMORY_SCOPE_AGENT) == g)
                    __builtin_amdgcn_s_sleep(1);
            }
        } else {
            while (__hip_atomic_load(ggen, __ATOMIC_ACQUIRE, __HIP_MEMORY_SCOPE_AGENT) == g)
                __builtin_amdgcn_s_sleep(1);
        }
        __threadfence();
    }
    __syncthreads();
}

// Block b owns K rows [16b, 16b+16) in LDS (128 KiB). Per iteration:
//  A: partial col sums -> P[b][0..4096)   (u block-local in su[])
//  B: reduce P over 256 blocks -> v[16b..16b+16)
//  C: LDS row-dots with v -> u (su[] + global)
__global__ __launch_bounds__(256, 1)
void sinkhorn_lds(const unsigned short* __restrict__ Kb,
                  float* __restrict__ u, float* __restrict__ v,
                  float* __restrict__ P, int* __restrict__ bar)
{
    __shared__ unsigned short sK[16 * 4096];   // 128 KiB
    __shared__ float su[16];
    __shared__ float red[256];

    int* lcnt = bar;
    int* gcnt = bar + NGRP;
    int* ggen = bar + NGRP + 1;

    const int t = threadIdx.x;
    const int b = blockIdx.x;
    const int w = t >> 6, lane = t & 63;
    const int row0 = b * 16;

    // one-time K strip load (coalesced, 32 uint4/thread)
    {
        const uint4* src = (const uint4*)(Kb + (size_t)row0 * 4096);
        uint4* dst = (uint4*)sK;
        #pragma unroll
        for (int k = 0; k < 32; ++k)
            dst[k * 256 + t] = src[k * 256 + t];
    }
    if (t < 16) su[t] = 1.0f / 4096.0f;
    __syncthreads();

    const int cbase = w * 1024 + lane * 8;     // ushort index within a row
    const int ccol = t & 15, cgrp = t >> 4;
    const int mycol = b * 16 + ccol;

    for (int it = 0; it < SINK_ITERS; ++it) {
        // ---- Phase A: P[b][j] = sum_i sK[i][j] * su[i]
        {
            float p[16];
            #pragma unroll
            for (int c = 0; c < 16; ++c) p[c] = 0.0f;
            #pragma unroll 4
            for (int i = 0; i < 16; ++i) {
                const float ui = su[i];
                const uint4 a = *(const uint4*)&sK[i * 4096 + cbase];
                const uint4 bq = *(const uint4*)&sK[i * 4096 + cbase + 512];
                p[0]  = fmaf(blo(a.x),  ui, p[0]);  p[1]  = fmaf(bhi(a.x),  ui, p[1]);
                p[2]  = fmaf(blo(a.y),  ui, p[2]);  p[3]  = fmaf(bhi(a.y),  ui, p[3]);
                p[4]  = fmaf(blo(a.z),  ui, p[4]);  p[5]  = fmaf(bhi(a.z),  ui, p[5]);
                p[6]  = fmaf(blo(a.w),  ui, p[6]);  p[7]  = fmaf(bhi(a.w),  ui, p[7]);
                p[8]  = fmaf(blo(bq.x), ui, p[8]);  p[9]  = fmaf(bhi(bq.x), ui, p[9]);
                p[10] = fmaf(blo(bq.y), ui, p[10]); p[11] = fmaf(bhi(bq.y), ui, p[11]);
                p[12] = fmaf(blo(bq.z), ui, p[12]); p[13] = fmaf(bhi(bq.z), ui, p[13]);
                p[14] = fmaf(blo(bq.w), ui, p[14]); p[15] = fmaf(bhi(bq.w), ui, p[15]);
            }
            float* Pb = P + (size_t)b * 4096 + cbase;
            *(float4*)&Pb[0]   = float4{p[0],  p[1],  p[2],  p[3]};
            *(float4*)&Pb[4]   = float4{p[4],  p[5],  p[6],  p[7]};
            *(float4*)&Pb[512] = float4{p[8],  p[9],  p[10], p[11]};
            *(float4*)&Pb[516] = float4{p[12], p[13], p[14], p[15]};
        }
        grid_barrier(lcnt, gcnt, ggen);

        // ---- Phase B: v[mycol] = (1/N) / sum_{b'} P[b'][mycol]
        {
            float s = 0.0f;
            #pragma unroll
            for (int k = 0; k < 16; ++k)
                s += P[(size_t)(cgrp + (k << 4)) * 4096 + mycol];
            red[t] = s;
            __syncthreads();
            if (cgrp < 8) red[t] += red[t + 128];
            __syncthreads();
            if (cgrp < 4) red[t] += red[t + 64];
            __syncthreads();
            if (cgrp < 2) red[t] += red[t + 32];
            __syncthreads();
            if (cgrp == 0) {
                const float tot = red[t] + red[t + 16];
                v[mycol] = (1.0f / 4096.0f) / tot;
            }
        }
        grid_barrier(lcnt, gcnt, ggen);

        // ---- Phase C: u[row] = (1/N) / dot(sK[row,:], v)
        #pragma unroll
        for (int rr = 0; rr < 4; ++rr) {
            const int i = w * 4 + rr;
            const uint4*  m4 = (const uint4*)&sK[i * 4096];
            const float4* x4 = (const float4*)v;
            float s0 = 0, s1 = 0, s2 = 0, s3 = 0;
            #pragma unroll
            for (int k = 0; k < 8; ++k) {
                const int q = (k << 6) + lane;
                const uint4  m  = m4[q];
                const float4 xa = x4[q * 2];
                const float4 xb = x4[q * 2 + 1];
                s0 = fmaf(blo(m.x), xa.x, s0); s1 = fmaf(bhi(m.x), xa.y, s1);
                s2 = fmaf(blo(m.y), xa.z, s2); s3 = fmaf(bhi(m.y), xa.w, s3);
                s0 = fmaf(blo(m.z), xb.x, s0); s1 = fmaf(bhi(m.z), xb.y, s1);
                s2 = fmaf(blo(m.w), xb.z, s2); s3 = fmaf(bhi(m.w), xb.w, s3);
            }
            float s = (s0 + s1) + (s2 + s3);
            #pragma unroll
            for (int o = 32; o > 0; o >>= 1) s += __shfl_down(s, o);
            if (lane == 0) {
                const float nu = (1.0f / 4096.0f) / s;
                su[i] = nu;
                u[row0 + i] = nu;
            }
        }
        __syncthreads();   // su visible to Phase A of next iteration
    }
}

} // namespace

extern "C" void kernel_launch(void* const* d_in, const int* in_sizes, int n_in,
                              void* d_out, int out_size, void* d_ws, size_t ws_size,
                              hipStream_t stream)
{
    const float* x  = (const float*)d_in[0];
    const float* zp = (const float*)d_in[1];
    const float* ew[4] = {(const float*)d_in[2],  (const float*)d_in[4],
                          (const float*)d_in[6],  (const float*)d_in[8]};
    const float* eb[4] = {(const float*)d_in[3],  (const float*)d_in[5],
                          (const float*)d_in[7],  (const float*)d_in[9]};
    const float* dw[4] = {(const float*)d_in[10], (const float*)d_in[12],
                          (const float*)d_in[14], (const float*)d_in[16]};
    const float* db[4] = {(const float*)d_in[11], (const float*)d_in[13],
                          (const float*)d_in[15], (const float*)d_in[17]};
    float* out = (float*)d_out;

    char* w = (char*)d_ws;
    size_t off = 0;
    auto alloc = [&](size_t bytes) {
        void* p = (void*)(w + off);
        off += (bytes + 255) & ~size_t(255);
        return p;
    };
    float* Mm = (float*)alloc((size_t)4096 * 4096 * 4);                 // 64 MiB
    unsigned short* Kb  = (unsigned short*)alloc((size_t)4096 * 4096 * 2);
    float* P = (float*)alloc((size_t)256 * 4096 * 4);                   // 4 MiB partials
    unsigned short* dwt0 = (unsigned short*)alloc((size_t)512  * 128 * 2);
    unsigned short* dwt1 = (unsigned short*)alloc((size_t)1024 * 512 * 2);
    unsigned short* dwt2 = (unsigned short*)alloc((size_t)512  * 1024 * 2);
    unsigned short* dwt3 = (unsigned short*)alloc((size_t)1024 * 512 * 2);
    unsigned short* W2t  = (unsigned short*)alloc((size_t)128 * 4096 * 2);
    unsigned short* zh  = (unsigned short*)alloc((size_t)4096 * 128 * 2);
    unsigned short* zl  = (unsigned short*)alloc((size_t)4096 * 128 * 2);
    unsigned short* zph = (unsigned short*)alloc((size_t)4096 * 128 * 2);
    unsigned short* zpl = (unsigned short*)alloc((size_t)4096 * 128 * 2);
    float* zn   = (float*)alloc(4096 * 4);
    float* pn   = (float*)alloc(4096 * 4);
    float* u    = (float*)alloc(4096 * 4);
    float* v    = (float*)alloc(4096 * 4);
    float* mx   = (float*)alloc(256);
    int*   bar  = (int*)alloc(32 * 4);
    (void)ws_size; (void)in_sizes; (void)n_in; (void)out_size;

    // --- encoder-phase aliases inside Mm (dead before cost GEMM writes Mm)
    char* m = (char*)Mm;
    unsigned short* w0th = (unsigned short*)(m + (size_t)0  * (1u << 20));
    unsigned short* w0tl = (unsigned short*)(m + (size_t)1  * (1u << 20));
    unsigned short* w1th = (unsigned short*)(m + (size_t)2  * (1u << 20));
    unsigned short* w1tl = (unsigned short*)(m + (size_t)3  * (1u << 20));
    unsigned short* w2th = (unsigned short*)(m + (size_t)4  * (1u << 20));
    unsigned short* w2tl = (unsigned short*)(m + (size_t)5  * (1u << 20));
    unsigned short* a0h  = (unsigned short*)(m + (size_t)6  * (1u << 20));
    unsigned short* a0l  = (unsigned short*)(m + (size_t)10 * (1u << 20));
    unsigned short* a1h  = (unsigned short*)(m + (size_t)14 * (1u << 20));
    unsigned short* a1l  = (unsigned short*)(m + (size_t)22 * (1u << 20));
    unsigned short* a2h  = (unsigned short*)(m + (size_t)30 * (1u << 20));
    unsigned short* a2l  = (unsigned short*)(m + (size_t)34 * (1u << 20));
    unsigned short* w3th = (unsigned short*)(m + (size_t)38 * (1u << 20));
    unsigned short* w3tl = (unsigned short*)(m + (size_t)39 * (1u << 20));
    // --- x splits inside Kb region (dead after L0; Kb written after encoder)
    unsigned short* xh = (unsigned short*)Kb;
    unsigned short* xl = (unsigned short*)((char*)Kb + ((size_t)8 << 20));
    // --- decoder activation aliases inside Mm (dead after exp_k)
    unsigned short* zselb = (unsigned short*)(m);
    unsigned short* a0b   = (unsigned short*)(m + (1u << 20));
    unsigned short* a1b   = (unsigned short*)(m + (5u << 20));
    unsigned short* a2b   = (unsigned short*)(m + (13u << 20));

    const dim3 blk(256);

    // ---- prep
    split_k<<<4096, blk, 0, stream>>>(x, xh, xl);
    prep_k<<<4752, blk, 0, stream>>>(zp, zph, zpl,
                                     ew[0], w0th, w0tl, ew[1], w1th, w1tl,
                                     ew[2], w2th, w2tl, ew[3], w3th, w3tl,
                                     dw[0], dwt0, dw[1], dwt1,
                                     dw[2], dwt2, dw[3], dwt3,
                                     pn, u, v, mx, bar);

    // ---- encoder: 1024 -> 512 -> 1024 -> 512 -> 128 (split-bf16x2 MFMA)
    gemm128_split<EPI_SPLIT_RELU><<<dim3(512/128,  4096/128), blk, 0, stream>>>(xh,  xl,  w0th, w0tl, eb[0], nullptr, a0h, a0l, nullptr, 4096, 512, 1024);
    gemm128_split<EPI_SPLIT_RELU><<<dim3(1024/128, 4096/128), blk, 0, stream>>>(a0h, a0l, w1th, w1tl, eb[1], nullptr, a1h, a1l, nullptr, 4096, 1024, 512);
    gemm128_split<EPI_SPLIT_RELU><<<dim3(512/128,  4096/128), blk, 0, stream>>>(a1h, a1l, w2th, w2tl, eb[2], nullptr, a2h, a2l, nullptr, 4096, 512, 1024);
    gemm_l3_fused<<<64, blk, 0, stream>>>(a2h, a2l, w3th, w3tl, eb[3], zh, zl, zn);

    // ---- cost matrix (split MFMA) + bf16 K (no transpose needed)
    gemm128_split<EPI_COST><<<dim3(4096/128, 4096/128), blk, 0, stream>>>(zh, zl, zph, zpl, zn, pn, Mm, nullptr, mx, 4096, 4096, 128);
    exp_k<<<8192, blk, 0, stream>>>(Mm, Kb, mx);
    // Mm dead; region reused for decoder activations.

    // ---- Sinkhorn: LDS-resident K, one persistent dispatch
    sinkhorn_lds<<<NBLK, blk, 0, stream>>>(Kb, u, v, P, bar);

    // ---- z_sel = diag(u) * K * (diag(v) * zp)   via bf16 MFMA
    vscale_t_k<<<dim3(128/32, 4096/32), blk, 0, stream>>>(zp, v, W2t);
    gemm_bf16_bt<false,true,true><<<dim3(128/64, 4096/64), blk, 0, stream>>>(Kb, W2t, nullptr, u, zselb, 4096, 128, 4096);

    // ---- decoder (bf16 MFMA): 128 -> 512 -> 1024 -> 512 -> 1024
    gemm_bf16_bt<true, true, false><<<dim3(512/64,  4096/64), blk, 0, stream>>>(zselb, dwt0, db[0], nullptr, a0b, 4096, 512, 128);
    gemm_bf16_bt<true, true, false><<<dim3(1024/64, 4096/64), blk, 0, stream>>>(a0b,   dwt1, db[1], nullptr, a1b, 4096, 1024, 512);
    gemm_bf16_bt<true, true, false><<<dim3(512/64,  4096/64), blk, 0, stream>>>(a1b,   dwt2, db[2], nullptr, a2b, 4096, 512, 1024);
    gemm_bf16_bt<false,false,false><<<dim3(1024/64, 4096/64), blk, 0, stream>>>(a2b,   dwt3, db[3], nullptr, out, 4096, 1024, 512);
}